// Round 5
// baseline (849.805 us; speedup 1.0000x reference)
//
#include <hip/hip_runtime.h>
#include <cstddef>

typedef _Float16 f16x8 __attribute__((ext_vector_type(8)));
typedef float    f32x4 __attribute__((ext_vector_type(4)));

#define Bc 4096
#define Tc 256
#define NSTEP 257
#define RB 16               // rows per block
#define HSTR 264            // fp16 h-tile row stride
#define HEAD_OFF 393216     // byte offset of head frags in ws

__device__ inline float sigm(float x)  { return __builtin_amdgcn_rcpf(1.f + __expf(-x)); }
__device__ inline float tanh_(float x) { return 1.f - 2.f * __builtin_amdgcn_rcpf(1.f + __expf(2.f * x)); }

// ---------------------------------------------------------------------------
// Build fragment-linear fp16 copies of w_hh and w_head in ws.
// w_hh frag f = (trio*3+nc)*8 + kt, 1024 B each:
//   element (lane l, j) = W[kt*32 + (l>>4)*8 + j][nc*256 + trio*16 + (l&15)]
// head frags at HEAD_OFF, kt = 0..7: col = l&15 (<2 real, else 0)
// ---------------------------------------------------------------------------
__global__ __launch_bounds__(256) void build_frags(
    const float* __restrict__ w_hh, const float* __restrict__ w_head,
    _Float16* __restrict__ ws)
{
    int flat = blockIdx.x * 256 + threadIdx.x;
    if (blockIdx.x < 96) {
        int f    = flat >> 6;          // 0..383
        int lane = flat & 63;
        int kt   = f & 7;
        int nc   = (f >> 3) % 3;
        int trio = f / 24;
        int c     = nc * 256 + trio * 16 + (lane & 15);
        int kbase = kt * 32 + (lane >> 4) * 8;
        _Float16* dst = ws + (size_t)f * 512 + (size_t)lane * 8;
        #pragma unroll
        for (int j = 0; j < 8; ++j)
            dst[j] = (_Float16)w_hh[(size_t)(kbase + j) * 768 + c];
    } else {
        int idx = flat - 96 * 256;     // 0..511
        int kt   = idx >> 6;
        int lane = idx & 63;
        int col   = lane & 15;
        int kbase = kt * 32 + (lane >> 4) * 8;
        _Float16* dst = ws + HEAD_OFF / 2 + (size_t)kt * 512 + (size_t)lane * 8;
        #pragma unroll
        for (int j = 0; j < 8; ++j)
            dst[j] = (col < 2) ? (_Float16)w_head[(size_t)(kbase + j) * 2 + col]
                               : (_Float16)0.f;
    }
}

// ---------------------------------------------------------------------------
// GRU scan: 256 blocks x 512 threads (8 waves), 16 rows per block.
// Wave w owns units [32w, 32w+32); 48 B-frags pinned in registers (AGPRs).
// SINGLE barrier per step: h double-buffered (MFMA reads h[cur], gate writes
// h[nxt]) -> waves drift across phases, MFMA overlaps gate-VALU across waves.
// outbuf is wave-0-private (w0 writes AND flushes) -> no sync needed for it.
// s_setprio(1) around the MFMA cluster (T5).
// ---------------------------------------------------------------------------
__global__ __attribute__((amdgpu_waves_per_eu(2, 2))) __launch_bounds__(512)
void gru_mfma(
    const float* __restrict__ cond, const float* __restrict__ ivf,
    const float* __restrict__ times,
    const float* __restrict__ w1, const float* __restrict__ b1,
    const float* __restrict__ w2, const float* __restrict__ b2,
    const float* __restrict__ w3, const float* __restrict__ b3,
    const float* __restrict__ wh0, const float* __restrict__ bh0,
    const float* __restrict__ w_ih, const float* __restrict__ b_ih,
    const float* __restrict__ b_hh, const float* __restrict__ b_head,
    const _Float16* __restrict__ wfrag,
    float* __restrict__ out)
{
    __shared__ __align__(16) _Float16 hA[RB * HSTR];      // 8448 B
    __shared__ __align__(16) _Float16 hB[RB * HSTR];      // 8448 B
    __shared__ float  xs[RB * NSTEP];                     // 16448 B
    __shared__ __align__(16) _Float16 headB[4096];        // 8192 B
    __shared__ float  gateC[256 * 8];                     // 8192 B
    __shared__ float  outbuf[2][RB][16];                  // 2048 B (w0-private)
    __shared__ float  bh2[2];
    __shared__ float  mlp1[RB * 128];
    __shared__ float  mlp2[RB * 128];
    __shared__ float  embS[RB * 64];
    __shared__ float  h0f[RB * 256];

    const int tid  = threadIdx.x;
    const int w    = tid >> 6;
    const int lane = tid & 63;
    const int l15  = lane & 15;
    const int q    = lane >> 4;
    const int row0 = blockIdx.x * RB;

    // ---- preamble: MLP + h0 for the block's 16 rows ----
    for (int o = tid; o < RB * 128; o += 512) {
        int r = o >> 7, c = o & 127;
        float a = b1[c];
        #pragma unroll 4
        for (int k = 0; k < 64; ++k)
            a = fmaf(ivf[(size_t)(row0 + r) * 64 + k], w1[k * 128 + c], a);
        mlp1[o] = fmaxf(a, 0.f);
    }
    __syncthreads();
    for (int o = tid; o < RB * 128; o += 512) {
        int r = o >> 7, c = o & 127;
        float a = b2[c];
        #pragma unroll 4
        for (int k = 0; k < 128; ++k)
            a = fmaf(mlp1[r * 128 + k], w2[k * 128 + c], a);
        mlp2[o] = fmaxf(a, 0.f);
    }
    __syncthreads();
    for (int o = tid; o < RB * 64; o += 512) {
        int r = o >> 6, c = o & 63;
        float a = b3[c];
        #pragma unroll 4
        for (int k = 0; k < 128; ++k)
            a = fmaf(mlp2[r * 128 + k], w3[k * 64 + c], a);
        embS[o] = a;
    }
    __syncthreads();
    for (int o = tid; o < RB * 256; o += 512) {
        int r = o >> 8, c = o & 255;
        float a = bh0[c];
        #pragma unroll 4
        for (int k = 0; k < 128; ++k)
            a = fmaf(cond[(size_t)(row0 + r) * 128 + k], wh0[k * 256 + c], a);
        #pragma unroll 4
        for (int k = 0; k < 64; ++k)
            a = fmaf(embS[r * 64 + k], wh0[(128 + k) * 256 + c], a);
        h0f[o] = tanh_(a);
    }
    __syncthreads();

    // fp16 h tile (buffer A), xs table, head-B staging, gate-constant table
    for (int o = tid; o < RB * 256; o += 512) {
        int r = o >> 8, c = o & 255;
        hA[r * HSTR + c] = (_Float16)h0f[o];
    }
    for (int o = tid; o < RB * NSTEP; o += 512) {
        int r = o / NSTEP, ii = o - r * NSTEP;
        float x = 0.f;
        if (ii >= 1) {
            float a = times[(size_t)(row0 + r) * Tc + (ii - 1)];
            float b = (ii >= 2) ? times[(size_t)(row0 + r) * Tc + (ii - 2)] : 0.f;
            x = a - b;
        }
        xs[o] = x;
    }
    {
        const float4* src = (const float4*)(wfrag + HEAD_OFF / 2);
        ((float4*)headB)[tid] = src[tid];
    }
    for (int uu = tid; uu < 256; uu += 512) {
        gateC[uu * 8 + 0] = w_ih[uu];
        gateC[uu * 8 + 1] = w_ih[256 + uu];
        gateC[uu * 8 + 2] = w_ih[512 + uu];
        gateC[uu * 8 + 3] = b_ih[uu] + b_hh[uu];
        gateC[uu * 8 + 4] = b_ih[256 + uu] + b_hh[256 + uu];
        gateC[uu * 8 + 5] = b_ih[512 + uu];
        gateC[uu * 8 + 6] = b_hh[512 + uu];
        gateC[uu * 8 + 7] = 0.f;
    }
    if (tid < 2) bh2[tid] = b_head[tid];

    // ---- register-resident weight fragments: 48 x f16x8 ----
    const int u0 = w * 32 + l15;
    const int u1 = u0 + 16;

    f16x8 Bf[2][3][8];
    #pragma unroll
    for (int p = 0; p < 2; ++p)
        #pragma unroll
        for (int nc = 0; nc < 3; ++nc)
            #pragma unroll
            for (int kt = 0; kt < 8; ++kt)
                Bf[p][nc][kt] = *(const f16x8*)(wfrag
                    + (size_t)(((2 * w + p) * 3 + nc) * 8 + kt) * 512
                    + (size_t)lane * 8);

    __syncthreads();

    float hold[2][4];
    #pragma unroll
    for (int p = 0; p < 2; ++p)
        #pragma unroll
        for (int j = 0; j < 4; ++j)
            hold[p][j] = h0f[(q * 4 + j) * 256 + (p ? u1 : u0)];

    // ---- one GRU step: MFMA from hc, gate writes hn, ONE barrier ----
    auto STEP = [&](const _Float16* hc, _Float16* hn, int i) {
        const bool doGh = (i < NSTEP);
        const bool doHd = (i >= 1) && (w == 0);

        f32x4 aR[2], aZ[2], aN[2];
        #pragma unroll
        for (int p = 0; p < 2; ++p) {
            aR[p] = (f32x4){0.f, 0.f, 0.f, 0.f};
            aZ[p] = (f32x4){0.f, 0.f, 0.f, 0.f};
            aN[p] = (f32x4){0.f, 0.f, 0.f, 0.f};
        }
        f32x4 aH = (f32x4){0.f, 0.f, 0.f, 0.f};

        __builtin_amdgcn_s_setprio(1);
        #pragma unroll
        for (int kt = 0; kt < 8; ++kt) {
            if (doGh || doHd) {
                f16x8 Af = *(const f16x8*)(hc + l15 * HSTR + kt * 32 + q * 8);
                if (doGh) {
                    #pragma unroll
                    for (int p = 0; p < 2; ++p) {
                        aR[p] = __builtin_amdgcn_mfma_f32_16x16x32_f16(Af, Bf[p][0][kt], aR[p], 0, 0, 0);
                        aZ[p] = __builtin_amdgcn_mfma_f32_16x16x32_f16(Af, Bf[p][1][kt], aZ[p], 0, 0, 0);
                        aN[p] = __builtin_amdgcn_mfma_f32_16x16x32_f16(Af, Bf[p][2][kt], aN[p], 0, 0, 0);
                    }
                }
                if (doHd) {
                    f16x8 Bh = *(const f16x8*)(headB + kt * 512 + lane * 8);
                    aH = __builtin_amdgcn_mfma_f32_16x16x32_f16(Af, Bh, aH, 0, 0, 0);
                }
            }
        }
        __builtin_amdgcn_s_setprio(0);

        // head staging + flush: wave-0 private, no cross-wave sync needed
        if (doHd) {
            const int o = i - 1;
            if (l15 < 2) {
                #pragma unroll
                for (int j = 0; j < 4; ++j)
                    outbuf[l15][q * 4 + j][o & 15] = aH[j];
            }
            if (((o & 15) == 15) || (o == NSTEP - 1)) {
                const int cnt   = (o & 15) + 1;
                const int obase = o & ~15;
                #pragma unroll
                for (int s = 0; s < 8; ++s) {
                    const int idx   = s * 64 + lane;
                    const int e     = idx & 15;
                    const int row   = (idx >> 4) & 15;
                    const int plane = idx >> 8;
                    if (e < cnt)
                        out[(size_t)plane * ((size_t)Bc * NSTEP)
                            + (size_t)(row0 + row) * NSTEP + obase + e]
                            = outbuf[plane][row][e] + bh2[plane];
                }
            }
        }

        if (doGh) {
            #pragma unroll
            for (int p = 0; p < 2; ++p) {
                const int u = p ? u1 : u0;
                const f32x4 g0 = *(const f32x4*)(gateC + u * 8);      // wiR,wiZ,wiN,bR
                const f32x4 g1 = *(const f32x4*)(gateC + u * 8 + 4);  // bZ,biN,bhN,pad
                #pragma unroll
                for (int j = 0; j < 4; ++j) {
                    const int m = q * 4 + j;
                    const float x  = xs[m * NSTEP + i];
                    const float rr = sigm(fmaf(x, g0[0], g0[3]) + aR[p][j]);
                    const float zz = sigm(fmaf(x, g0[1], g1[0]) + aZ[p][j]);
                    const float nn = tanh_(fmaf(x, g0[2], g1[1]) + rr * (aN[p][j] + g1[2]));
                    const float hn_ = nn + zz * (hold[p][j] - nn);
                    hold[p][j] = hn_;
                    hn[m * HSTR + u] = (_Float16)hn_;
                }
            }
        }
        __syncthreads();   // h[nxt] complete and visible; next step may write h[cur]
    };

    // 257 GRU steps + 1 head-only epilogue = 258 iterations (even)
    for (int i = 0; i < NSTEP + 1; i += 2) {
        STEP(hA, hB, i);
        STEP(hB, hA, i + 1);
    }
}

// ---------------------------------------------------------------------------
extern "C" void kernel_launch(void* const* d_in, const int* in_sizes, int n_in,
                              void* d_out, int out_size, void* d_ws, size_t ws_size,
                              hipStream_t stream) {
    const float* cond   = (const float*)d_in[0];
    const float* ivf    = (const float*)d_in[1];
    const float* times  = (const float*)d_in[2];
    // d_in[3] = seq_lens (unused by reference)
    const float* w1     = (const float*)d_in[4];
    const float* b1     = (const float*)d_in[5];
    const float* w2     = (const float*)d_in[6];
    const float* b2     = (const float*)d_in[7];
    const float* w3     = (const float*)d_in[8];
    const float* b3     = (const float*)d_in[9];
    const float* wh0    = (const float*)d_in[10];
    const float* bh0    = (const float*)d_in[11];
    const float* w_ih   = (const float*)d_in[12];
    const float* b_ih   = (const float*)d_in[13];
    const float* w_hh   = (const float*)d_in[14];
    const float* b_hh   = (const float*)d_in[15];
    const float* w_head = (const float*)d_in[16];
    const float* b_head = (const float*)d_in[17];

    float*    outp = (float*)d_out;
    _Float16* ws   = (_Float16*)d_ws;

    build_frags<<<98, 256, 0, stream>>>(w_hh, w_head, ws);
    gru_mfma<<<Bc / RB, 512, 0, stream>>>(cond, ivf, times,
                                          w1, b1, w2, b2, w3, b3, wh0, bh0,
                                          w_ih, b_ih, b_hh, b_head,
                                          (const _Float16*)ws, outp);
}

// Round 6
// 836.214 us; speedup vs baseline: 1.0163x; 1.0163x over previous
//
#include <hip/hip_runtime.h>
#include <cstddef>

typedef _Float16 f16x8 __attribute__((ext_vector_type(8)));
typedef float    f32x4 __attribute__((ext_vector_type(4)));

#define Bc 4096
#define Tc 256
#define NSTEP 257
#define RB 16               // rows per block
#define HSTR 264            // fp16 h-tile row stride
#define HEAD_OFF 393216     // byte offset of head frags in ws

__device__ inline float sigm(float x)  { return __builtin_amdgcn_rcpf(1.f + __expf(-x)); }
__device__ inline float tanh_(float x) { return 1.f - 2.f * __builtin_amdgcn_rcpf(1.f + __expf(2.f * x)); }

// ---------------------------------------------------------------------------
// Build fragment-linear fp16 copies of w_hh and w_head in ws.
// w_hh frag f = (trio*3+nc)*8 + kt, 1024 B each:
//   element (lane l, j) = W[kt*32 + (l>>4)*8 + j][nc*256 + trio*16 + (l&15)]
// head frags at HEAD_OFF, kt = 0..7: col = l&15 (<2 real, else 0)
// ---------------------------------------------------------------------------
__global__ __launch_bounds__(256) void build_frags(
    const float* __restrict__ w_hh, const float* __restrict__ w_head,
    _Float16* __restrict__ ws)
{
    int flat = blockIdx.x * 256 + threadIdx.x;
    if (blockIdx.x < 96) {
        int f    = flat >> 6;          // 0..383
        int lane = flat & 63;
        int kt   = f & 7;
        int nc   = (f >> 3) % 3;
        int trio = f / 24;
        int c     = nc * 256 + trio * 16 + (lane & 15);
        int kbase = kt * 32 + (lane >> 4) * 8;
        _Float16* dst = ws + (size_t)f * 512 + (size_t)lane * 8;
        #pragma unroll
        for (int j = 0; j < 8; ++j)
            dst[j] = (_Float16)w_hh[(size_t)(kbase + j) * 768 + c];
    } else {
        int idx = flat - 96 * 256;     // 0..511
        int kt   = idx >> 6;
        int lane = idx & 63;
        int col   = lane & 15;
        int kbase = kt * 32 + (lane >> 4) * 8;
        _Float16* dst = ws + HEAD_OFF / 2 + (size_t)kt * 512 + (size_t)lane * 8;
        #pragma unroll
        for (int j = 0; j < 8; ++j)
            dst[j] = (col < 2) ? (_Float16)w_head[(size_t)(kbase + j) * 2 + col]
                               : (_Float16)0.f;
    }
}

// ---------------------------------------------------------------------------
// GRU scan: 256 blocks x 512 threads (8 waves), 16 rows per block.
// Wave w owns units [32w, 32w+32); 48 B-frags pinned in registers/AGPRs.
// ONE barrier per step (h double-buffered hA/hB). Output flushed at TOP of
// step (post-barrier) by all 512 threads from a parity-double-buffered LDS
// staging buffer -> coalesced 64B-line writes, no extra barrier, no race.
// No setprio. Depth-1 A-frag software pipeline keeps register pressure low.
// ---------------------------------------------------------------------------
__global__ __attribute__((amdgpu_waves_per_eu(2, 2))) __launch_bounds__(512)
void gru_mfma(
    const float* __restrict__ cond, const float* __restrict__ ivf,
    const float* __restrict__ times,
    const float* __restrict__ w1, const float* __restrict__ b1,
    const float* __restrict__ w2, const float* __restrict__ b2,
    const float* __restrict__ w3, const float* __restrict__ b3,
    const float* __restrict__ wh0, const float* __restrict__ bh0,
    const float* __restrict__ w_ih, const float* __restrict__ b_ih,
    const float* __restrict__ b_hh, const float* __restrict__ b_head,
    const _Float16* __restrict__ wfrag,
    float* __restrict__ out)
{
    __shared__ __align__(16) _Float16 hA[RB * HSTR];      // 8448 B
    __shared__ __align__(16) _Float16 hB[RB * HSTR];      // 8448 B
    __shared__ __align__(16) float xs4[4 * NSTEP * 4];    // 16448 B  [q][i][4]
    __shared__ __align__(16) _Float16 headB[4096];        // 8192 B
    __shared__ float  gateC[256 * 8];                     // 8192 B
    __shared__ float  outbuf[2][2][RB][16];               // 4096 B [parity][plane][row][slot]
    __shared__ float  bh2[2];
    __shared__ float  mlp1[RB * 128];
    __shared__ float  mlp2[RB * 128];
    __shared__ float  embS[RB * 64];
    __shared__ float  h0f[RB * 256];

    const int tid  = threadIdx.x;
    const int w    = tid >> 6;
    const int lane = tid & 63;
    const int l15  = lane & 15;
    const int q    = lane >> 4;
    const int row0 = blockIdx.x * RB;

    // ---- preamble: MLP + h0 for the block's 16 rows ----
    for (int o = tid; o < RB * 128; o += 512) {
        int r = o >> 7, c = o & 127;
        float a = b1[c];
        #pragma unroll 4
        for (int k = 0; k < 64; ++k)
            a = fmaf(ivf[(size_t)(row0 + r) * 64 + k], w1[k * 128 + c], a);
        mlp1[o] = fmaxf(a, 0.f);
    }
    __syncthreads();
    for (int o = tid; o < RB * 128; o += 512) {
        int r = o >> 7, c = o & 127;
        float a = b2[c];
        #pragma unroll 4
        for (int k = 0; k < 128; ++k)
            a = fmaf(mlp1[r * 128 + k], w2[k * 128 + c], a);
        mlp2[o] = fmaxf(a, 0.f);
    }
    __syncthreads();
    for (int o = tid; o < RB * 64; o += 512) {
        int r = o >> 6, c = o & 63;
        float a = b3[c];
        #pragma unroll 4
        for (int k = 0; k < 128; ++k)
            a = fmaf(mlp2[r * 128 + k], w3[k * 64 + c], a);
        embS[o] = a;
    }
    __syncthreads();
    for (int o = tid; o < RB * 256; o += 512) {
        int r = o >> 8, c = o & 255;
        float a = bh0[c];
        #pragma unroll 4
        for (int k = 0; k < 128; ++k)
            a = fmaf(cond[(size_t)(row0 + r) * 128 + k], wh0[k * 256 + c], a);
        #pragma unroll 4
        for (int k = 0; k < 64; ++k)
            a = fmaf(embS[r * 64 + k], wh0[(128 + k) * 256 + c], a);
        h0f[o] = tanh_(a);
    }
    __syncthreads();

    // fp16 h tile (buffer A), xs4 table, head-B staging, gate-constant table
    for (int o = tid; o < RB * 256; o += 512) {
        int r = o >> 8, c = o & 255;
        hA[r * HSTR + c] = (_Float16)h0f[o];
    }
    for (int o = tid; o < 4 * NSTEP; o += 512) {
        int qg = o / NSTEP, ii = o - qg * NSTEP;
        #pragma unroll
        for (int jj = 0; jj < 4; ++jj) {
            int r = qg * 4 + jj;
            float x = 0.f;
            if (ii >= 1) {
                float a = times[(size_t)(row0 + r) * Tc + (ii - 1)];
                float b = (ii >= 2) ? times[(size_t)(row0 + r) * Tc + (ii - 2)] : 0.f;
                x = a - b;
            }
            xs4[o * 4 + jj] = x;
        }
    }
    {
        const float4* src = (const float4*)(wfrag + HEAD_OFF / 2);
        ((float4*)headB)[tid] = src[tid];
    }
    for (int uu = tid; uu < 256; uu += 512) {
        gateC[uu * 8 + 0] = w_ih[uu];
        gateC[uu * 8 + 1] = w_ih[256 + uu];
        gateC[uu * 8 + 2] = w_ih[512 + uu];
        gateC[uu * 8 + 3] = b_ih[uu] + b_hh[uu];
        gateC[uu * 8 + 4] = b_ih[256 + uu] + b_hh[256 + uu];
        gateC[uu * 8 + 5] = b_ih[512 + uu];
        gateC[uu * 8 + 6] = b_hh[512 + uu];
        gateC[uu * 8 + 7] = 0.f;
    }
    if (tid < 2) bh2[tid] = b_head[tid];

    // ---- register-resident weight fragments: 48 x f16x8 ----
    const int u0 = w * 32 + l15;
    const int u1 = u0 + 16;

    f16x8 Bf[2][3][8];
    #pragma unroll
    for (int p = 0; p < 2; ++p)
        #pragma unroll
        for (int nc = 0; nc < 3; ++nc)
            #pragma unroll
            for (int kt = 0; kt < 8; ++kt)
                Bf[p][nc][kt] = *(const f16x8*)(wfrag
                    + (size_t)(((2 * w + p) * 3 + nc) * 8 + kt) * 512
                    + (size_t)lane * 8);

    __syncthreads();

    float hold[2][4];
    #pragma unroll
    for (int p = 0; p < 2; ++p)
        #pragma unroll
        for (int j = 0; j < 4; ++j)
            hold[p][j] = h0f[(q * 4 + j) * 256 + (p ? u1 : u0)];

    // ---- one GRU step; ONE barrier at the end ----
    auto STEP = [&](const _Float16* hc, _Float16* hn, int i) {
        // 1. flush a completed 16-output chunk (post-barrier of prev step).
        //    chunk [16k, 16k+15] complete after step 16k+16 -> flush at i=16k+17.
        if (i >= 2 && ((i - 2) & 15) == 15) {
            const int obase = i - 17;            // 16k
            const int par   = (obase >> 4) & 1;
            const int e     = tid & 15;
            const int row   = (tid >> 4) & 15;
            const int plane = tid >> 8;
            out[(size_t)plane * ((size_t)Bc * NSTEP)
                + (size_t)(row0 + row) * NSTEP + obase + e]
                = outbuf[par][plane][row][e] + bh2[plane];
        }

        const bool doGh = (i < NSTEP);
        const bool doHd = (i >= 1) && (w == 0);

        f32x4 aR[2], aZ[2], aN[2];
        #pragma unroll
        for (int p = 0; p < 2; ++p) {
            aR[p] = (f32x4){0.f, 0.f, 0.f, 0.f};
            aZ[p] = (f32x4){0.f, 0.f, 0.f, 0.f};
            aN[p] = (f32x4){0.f, 0.f, 0.f, 0.f};
        }
        f32x4 aH = (f32x4){0.f, 0.f, 0.f, 0.f};

        // 2. MFMA phase, depth-1 A-frag pipeline
        const _Float16* abase = hc + l15 * HSTR + q * 8;
        f16x8 Afc = *(const f16x8*)(abase);
        #pragma unroll
        for (int kt = 0; kt < 8; ++kt) {
            f16x8 Afn;
            if (kt < 7) Afn = *(const f16x8*)(abase + (kt + 1) * 32);
            if (doGh) {
                #pragma unroll
                for (int p = 0; p < 2; ++p) {
                    aR[p] = __builtin_amdgcn_mfma_f32_16x16x32_f16(Afc, Bf[p][0][kt], aR[p], 0, 0, 0);
                    aZ[p] = __builtin_amdgcn_mfma_f32_16x16x32_f16(Afc, Bf[p][1][kt], aZ[p], 0, 0, 0);
                    aN[p] = __builtin_amdgcn_mfma_f32_16x16x32_f16(Afc, Bf[p][2][kt], aN[p], 0, 0, 0);
                }
            }
            if (doHd) {
                f16x8 Bh = *(const f16x8*)(headB + kt * 512 + lane * 8);
                aH = __builtin_amdgcn_mfma_f32_16x16x32_f16(Afc, Bh, aH, 0, 0, 0);
            }
            Afc = Afn;
        }

        // 3. stage head results (w0 only), parity buffer
        if (doHd && l15 < 2) {
            const int o = i - 1;
            #pragma unroll
            for (int j = 0; j < 4; ++j)
                outbuf[(o >> 4) & 1][l15][q * 4 + j][o & 15] = aH[j];
        }

        // 4. gate phase -> write h_{i+1} into hn
        if (doGh) {
            const f32x4 xv = *(const f32x4*)(xs4 + (q * NSTEP + i) * 4);
            #pragma unroll
            for (int p = 0; p < 2; ++p) {
                const int u = p ? u1 : u0;
                const f32x4 g0 = *(const f32x4*)(gateC + u * 8);      // wiR,wiZ,wiN,bR
                const f32x4 g1 = *(const f32x4*)(gateC + u * 8 + 4);  // bZ,biN,bhN,pad
                #pragma unroll
                for (int j = 0; j < 4; ++j) {
                    const int m = q * 4 + j;
                    const float x  = xv[j];
                    const float rr = sigm(fmaf(x, g0[0], g0[3]) + aR[p][j]);
                    const float zz = sigm(fmaf(x, g0[1], g1[0]) + aZ[p][j]);
                    const float nn = tanh_(fmaf(x, g0[2], g1[1]) + rr * (aN[p][j] + g1[2]));
                    const float hn_ = nn + zz * (hold[p][j] - nn);
                    hold[p][j] = hn_;
                    hn[m * HSTR + u] = (_Float16)hn_;
                }
            }
        }
        __syncthreads();   // h_{i+1} + outbuf slot visible to everyone
    };

    // steps 0..257 (257 GRU steps + head-only epilogue), pairs for hA/hB flip
    for (int i = 0; i < NSTEP + 1; i += 2) {
        STEP(hA, hB, i);
        STEP(hB, hA, i + 1);
    }

    // final flushes: chunk [240..255] flushed at i=257; output 256 still staged
    {
        const int e     = tid & 15;
        const int row   = (tid >> 4) & 15;
        const int plane = tid >> 8;
        if (e < 1) {   // obase = 256, cnt = 1, parity (256>>4)&1 = 0
            out[(size_t)plane * ((size_t)Bc * NSTEP)
                + (size_t)(row0 + row) * NSTEP + 256 + e]
                = outbuf[0][plane][row][e] + bh2[plane];
        }
    }
}

// ---------------------------------------------------------------------------
extern "C" void kernel_launch(void* const* d_in, const int* in_sizes, int n_in,
                              void* d_out, int out_size, void* d_ws, size_t ws_size,
                              hipStream_t stream) {
    const float* cond   = (const float*)d_in[0];
    const float* ivf    = (const float*)d_in[1];
    const float* times  = (const float*)d_in[2];
    // d_in[3] = seq_lens (unused by reference)
    const float* w1     = (const float*)d_in[4];
    const float* b1     = (const float*)d_in[5];
    const float* w2     = (const float*)d_in[6];
    const float* b2     = (const float*)d_in[7];
    const float* w3     = (const float*)d_in[8];
    const float* b3     = (const float*)d_in[9];
    const float* wh0    = (const float*)d_in[10];
    const float* bh0    = (const float*)d_in[11];
    const float* w_ih   = (const float*)d_in[12];
    const float* b_ih   = (const float*)d_in[13];
    const float* w_hh   = (const float*)d_in[14];
    const float* b_hh   = (const float*)d_in[15];
    const float* w_head = (const float*)d_in[16];
    const float* b_head = (const float*)d_in[17];

    float*    outp = (float*)d_out;
    _Float16* ws   = (_Float16*)d_ws;

    build_frags<<<98, 256, 0, stream>>>(w_hh, w_head, ws);
    gru_mfma<<<Bc / RB, 512, 0, stream>>>(cond, ivf, times,
                                          w1, b1, w2, b2, w3, b3, wh0, bh0,
                                          w_ih, b_ih, b_hh, b_head,
                                          (const _Float16*)ws, outp);
}

// Round 7
// 769.194 us; speedup vs baseline: 1.1048x; 1.0871x over previous
//
#include <hip/hip_runtime.h>
#include <cstddef>

typedef _Float16 f16x8 __attribute__((ext_vector_type(8)));
typedef float    f32x4 __attribute__((ext_vector_type(4)));

#define Bc 4096
#define Tc 256
#define NSTEP 257
#define RB 16               // rows per block
#define HSTR 264            // fp16 h-tile row stride
#define FSTR 260            // f32 h-state row stride (2-way conflict = free)
#define HEAD_OFF 393216     // byte offset of head frags in ws

__device__ inline float sigm(float x)  { return __builtin_amdgcn_rcpf(1.f + __expf(-x)); }
__device__ inline float tanh_(float x) { return 1.f - 2.f * __builtin_amdgcn_rcpf(1.f + __expf(2.f * x)); }

// ---------------------------------------------------------------------------
// Build fragment-linear fp16 copies of w_hh and w_head in ws.
// w_hh frag f = (trio*3+nc)*8 + kt, 1024 B each:
//   element (lane l, j) = W[kt*32 + (l>>4)*8 + j][nc*256 + trio*16 + (l&15)]
// head frags at HEAD_OFF, kt = 0..7: col = l&15 (<2 real, else 0)
// ---------------------------------------------------------------------------
__global__ __launch_bounds__(256) void build_frags(
    const float* __restrict__ w_hh, const float* __restrict__ w_head,
    _Float16* __restrict__ ws)
{
    int flat = blockIdx.x * 256 + threadIdx.x;
    if (blockIdx.x < 96) {
        int f    = flat >> 6;          // 0..383
        int lane = flat & 63;
        int kt   = f & 7;
        int nc   = (f >> 3) % 3;
        int trio = f / 24;
        int c     = nc * 256 + trio * 16 + (lane & 15);
        int kbase = kt * 32 + (lane >> 4) * 8;
        _Float16* dst = ws + (size_t)f * 512 + (size_t)lane * 8;
        #pragma unroll
        for (int j = 0; j < 8; ++j)
            dst[j] = (_Float16)w_hh[(size_t)(kbase + j) * 768 + c];
    } else {
        int idx = flat - 96 * 256;     // 0..511
        int kt   = idx >> 6;
        int lane = idx & 63;
        int col   = lane & 15;
        int kbase = kt * 32 + (lane >> 4) * 8;
        _Float16* dst = ws + HEAD_OFF / 2 + (size_t)kt * 512 + (size_t)lane * 8;
        #pragma unroll
        for (int j = 0; j < 8; ++j)
            dst[j] = (col < 2) ? (_Float16)w_head[(size_t)(kbase + j) * 2 + col]
                               : (_Float16)0.f;
    }
}

// ---------------------------------------------------------------------------
// GRU scan: 256 blocks x 512 threads (8 waves), 16 rows per block.
// Wave w owns units [32w, 32w+32); 48 B-frags pinned in registers/AGPRs.
// ONE barrier per step (h double-buffered hA/hB). f32 recurrence state lives
// in LDS hF (thread-private access pattern -> no sync; saves 8 VGPRs).
// No A-frag pipeline (saves 8 VGPRs): peak live set ~228 < 256 budget.
// Output flushed at TOP of step from parity-double-buffered LDS staging.
// ---------------------------------------------------------------------------
__global__ __attribute__((amdgpu_waves_per_eu(2, 2))) __launch_bounds__(512)
void gru_mfma(
    const float* __restrict__ cond, const float* __restrict__ ivf,
    const float* __restrict__ times,
    const float* __restrict__ w1, const float* __restrict__ b1,
    const float* __restrict__ w2, const float* __restrict__ b2,
    const float* __restrict__ w3, const float* __restrict__ b3,
    const float* __restrict__ wh0, const float* __restrict__ bh0,
    const float* __restrict__ w_ih, const float* __restrict__ b_ih,
    const float* __restrict__ b_hh, const float* __restrict__ b_head,
    const _Float16* __restrict__ wfrag,
    float* __restrict__ out)
{
    __shared__ __align__(16) _Float16 hA[RB * HSTR];      // 8448 B
    __shared__ __align__(16) _Float16 hB[RB * HSTR];      // 8448 B
    __shared__ float  hF[RB * FSTR];                      // 16640 B f32 h-state
    __shared__ __align__(16) float xs4[4 * NSTEP * 4];    // 16448 B  [q][i][4]
    __shared__ __align__(16) _Float16 headB[4096];        // 8192 B
    __shared__ float  gateC[256 * 8];                     // 8192 B
    __shared__ float  outbuf[2][2][RB][16];               // 4096 B [parity][plane][row][slot]
    __shared__ float  bh2[2];
    __shared__ float  mlp1[RB * 128];                     // 8192 B
    __shared__ float  mlp2[RB * 128];                     // 8192 B
    __shared__ float  embS[RB * 64];                      // 4096 B

    const int tid  = threadIdx.x;
    const int w    = tid >> 6;
    const int lane = tid & 63;
    const int l15  = lane & 15;
    const int q    = lane >> 4;
    const int row0 = blockIdx.x * RB;

    // ---- preamble: MLP + h0 for the block's 16 rows ----
    for (int o = tid; o < RB * 128; o += 512) {
        int r = o >> 7, c = o & 127;
        float a = b1[c];
        #pragma unroll 4
        for (int k = 0; k < 64; ++k)
            a = fmaf(ivf[(size_t)(row0 + r) * 64 + k], w1[k * 128 + c], a);
        mlp1[o] = fmaxf(a, 0.f);
    }
    __syncthreads();
    for (int o = tid; o < RB * 128; o += 512) {
        int r = o >> 7, c = o & 127;
        float a = b2[c];
        #pragma unroll 4
        for (int k = 0; k < 128; ++k)
            a = fmaf(mlp1[r * 128 + k], w2[k * 128 + c], a);
        mlp2[o] = fmaxf(a, 0.f);
    }
    __syncthreads();
    for (int o = tid; o < RB * 64; o += 512) {
        int r = o >> 6, c = o & 63;
        float a = b3[c];
        #pragma unroll 4
        for (int k = 0; k < 128; ++k)
            a = fmaf(mlp2[r * 128 + k], w3[k * 64 + c], a);
        embS[o] = a;
    }
    __syncthreads();
    for (int o = tid; o < RB * 256; o += 512) {
        int r = o >> 8, c = o & 255;
        float a = bh0[c];
        #pragma unroll 4
        for (int k = 0; k < 128; ++k)
            a = fmaf(cond[(size_t)(row0 + r) * 128 + k], wh0[k * 256 + c], a);
        #pragma unroll 4
        for (int k = 0; k < 64; ++k)
            a = fmaf(embS[r * 64 + k], wh0[(128 + k) * 256 + c], a);
        float h = tanh_(a);
        hF[r * FSTR + c] = h;             // f32 recurrence state
        hA[r * HSTR + c] = (_Float16)h;   // fp16 MFMA operand
    }

    // xs4 table, head-B staging, gate-constant table (no barrier needed yet)
    for (int o = tid; o < 4 * NSTEP; o += 512) {
        int qg = o / NSTEP, ii = o - qg * NSTEP;
        #pragma unroll
        for (int jj = 0; jj < 4; ++jj) {
            int r = qg * 4 + jj;
            float x = 0.f;
            if (ii >= 1) {
                float a = times[(size_t)(row0 + r) * Tc + (ii - 1)];
                float b = (ii >= 2) ? times[(size_t)(row0 + r) * Tc + (ii - 2)] : 0.f;
                x = a - b;
            }
            xs4[o * 4 + jj] = x;
        }
    }
    {
        const float4* src = (const float4*)(wfrag + HEAD_OFF / 2);
        ((float4*)headB)[tid] = src[tid];
    }
    for (int uu = tid; uu < 256; uu += 512) {
        gateC[uu * 8 + 0] = w_ih[uu];
        gateC[uu * 8 + 1] = w_ih[256 + uu];
        gateC[uu * 8 + 2] = w_ih[512 + uu];
        gateC[uu * 8 + 3] = b_ih[uu] + b_hh[uu];
        gateC[uu * 8 + 4] = b_ih[256 + uu] + b_hh[256 + uu];
        gateC[uu * 8 + 5] = b_ih[512 + uu];
        gateC[uu * 8 + 6] = b_hh[512 + uu];
        gateC[uu * 8 + 7] = 0.f;
    }
    if (tid < 2) bh2[tid] = b_head[tid];

    // ---- register-resident weight fragments: 48 x f16x8 ----
    const int u0 = w * 32 + l15;
    const int u1 = u0 + 16;

    f16x8 Bf[2][3][8];
    #pragma unroll
    for (int p = 0; p < 2; ++p)
        #pragma unroll
        for (int nc = 0; nc < 3; ++nc)
            #pragma unroll
            for (int kt = 0; kt < 8; ++kt)
                Bf[p][nc][kt] = *(const f16x8*)(wfrag
                    + (size_t)(((2 * w + p) * 3 + nc) * 8 + kt) * 512
                    + (size_t)lane * 8);

    __syncthreads();

    // ---- one GRU step; ONE barrier at the end ----
    auto STEP = [&](const _Float16* hc, _Float16* hn, int i) {
        // 1. flush a completed 16-output chunk (chunk 16k flushes at i=16k+17)
        if (i >= 2 && ((i - 2) & 15) == 15) {
            const int obase = i - 17;            // 16k
            const int par   = (obase >> 4) & 1;
            const int e     = tid & 15;
            const int row   = (tid >> 4) & 15;
            const int plane = tid >> 8;
            out[(size_t)plane * ((size_t)Bc * NSTEP)
                + (size_t)(row0 + row) * NSTEP + obase + e]
                = outbuf[par][plane][row][e] + bh2[plane];
        }

        const bool doGh = (i < NSTEP);
        const bool doHd = (i >= 1) && (w == 0);

        f32x4 aR[2], aZ[2], aN[2];
        #pragma unroll
        for (int p = 0; p < 2; ++p) {
            aR[p] = (f32x4){0.f, 0.f, 0.f, 0.f};
            aZ[p] = (f32x4){0.f, 0.f, 0.f, 0.f};
            aN[p] = (f32x4){0.f, 0.f, 0.f, 0.f};
        }
        f32x4 aH = (f32x4){0.f, 0.f, 0.f, 0.f};

        // 2. MFMA phase
        const _Float16* abase = hc + l15 * HSTR + q * 8;
        #pragma unroll
        for (int kt = 0; kt < 8; ++kt) {
            f16x8 Af = *(const f16x8*)(abase + kt * 32);
            if (doGh) {
                #pragma unroll
                for (int p = 0; p < 2; ++p) {
                    aR[p] = __builtin_amdgcn_mfma_f32_16x16x32_f16(Af, Bf[p][0][kt], aR[p], 0, 0, 0);
                    aZ[p] = __builtin_amdgcn_mfma_f32_16x16x32_f16(Af, Bf[p][1][kt], aZ[p], 0, 0, 0);
                    aN[p] = __builtin_amdgcn_mfma_f32_16x16x32_f16(Af, Bf[p][2][kt], aN[p], 0, 0, 0);
                }
            }
            if (doHd) {
                f16x8 Bh = *(const f16x8*)(headB + kt * 512 + lane * 8);
                aH = __builtin_amdgcn_mfma_f32_16x16x32_f16(Af, Bh, aH, 0, 0, 0);
            }
        }

        // 3. stage head results (w0 only), parity buffer
        if (doHd && l15 < 2) {
            const int o = i - 1;
            #pragma unroll
            for (int j = 0; j < 4; ++j)
                outbuf[(o >> 4) & 1][l15][q * 4 + j][o & 15] = aH[j];
        }

        // 4. gate phase -> h_{i+1}: f32 state in hF (thread-private), fp16 to hn
        if (doGh) {
            const f32x4 xv = *(const f32x4*)(xs4 + (q * NSTEP + i) * 4);
            #pragma unroll
            for (int p = 0; p < 2; ++p) {
                const int u = p ? u1 : u0;
                const f32x4 g0 = *(const f32x4*)(gateC + u * 8);      // wiR,wiZ,wiN,bR
                const f32x4 g1 = *(const f32x4*)(gateC + u * 8 + 4);  // bZ,biN,bhN,pad
                #pragma unroll
                for (int j = 0; j < 4; ++j) {
                    const int m = q * 4 + j;
                    const float x  = xv[j];
                    const float ho = hF[m * FSTR + u];
                    const float rr = sigm(fmaf(x, g0[0], g0[3]) + aR[p][j]);
                    const float zz = sigm(fmaf(x, g0[1], g1[0]) + aZ[p][j]);
                    const float nn = tanh_(fmaf(x, g0[2], g1[1]) + rr * (aN[p][j] + g1[2]));
                    const float hn_ = nn + zz * (ho - nn);
                    hF[m * FSTR + u] = hn_;
                    hn[m * HSTR + u] = (_Float16)hn_;
                }
            }
        }
        __syncthreads();   // h_{i+1} + outbuf slot visible to everyone
    };

    // steps 0..257 (257 GRU steps + head-only epilogue), pairs for hA/hB flip
    for (int i = 0; i < NSTEP + 1; i += 2) {
        STEP(hA, hB, i);
        STEP(hB, hA, i + 1);
    }

    // final flush: output index 256 (parity 0), staged at step 257
    {
        const int e     = tid & 15;
        const int row   = (tid >> 4) & 15;
        const int plane = tid >> 8;
        if (e < 1) {
            out[(size_t)plane * ((size_t)Bc * NSTEP)
                + (size_t)(row0 + row) * NSTEP + 256 + e]
                = outbuf[0][plane][row][e] + bh2[plane];
        }
    }
}

// ---------------------------------------------------------------------------
extern "C" void kernel_launch(void* const* d_in, const int* in_sizes, int n_in,
                              void* d_out, int out_size, void* d_ws, size_t ws_size,
                              hipStream_t stream) {
    const float* cond   = (const float*)d_in[0];
    const float* ivf    = (const float*)d_in[1];
    const float* times  = (const float*)d_in[2];
    // d_in[3] = seq_lens (unused by reference)
    const float* w1     = (const float*)d_in[4];
    const float* b1     = (const float*)d_in[5];
    const float* w2     = (const float*)d_in[6];
    const float* b2     = (const float*)d_in[7];
    const float* w3     = (const float*)d_in[8];
    const float* b3     = (const float*)d_in[9];
    const float* wh0    = (const float*)d_in[10];
    const float* bh0    = (const float*)d_in[11];
    const float* w_ih   = (const float*)d_in[12];
    const float* b_ih   = (const float*)d_in[13];
    const float* w_hh   = (const float*)d_in[14];
    const float* b_hh   = (const float*)d_in[15];
    const float* w_head = (const float*)d_in[16];
    const float* b_head = (const float*)d_in[17];

    float*    outp = (float*)d_out;
    _Float16* ws   = (_Float16*)d_ws;

    build_frags<<<98, 256, 0, stream>>>(w_hh, w_head, ws);
    gru_mfma<<<Bc / RB, 512, 0, stream>>>(cond, ivf, times,
                                          w1, b1, w2, b2, w3, b3, wh0, bh0,
                                          w_ih, b_ih, b_hh, b_head,
                                          (const _Float16*)ws, outp);
}

// Round 8
// 705.124 us; speedup vs baseline: 1.2052x; 1.0909x over previous
//
#include <hip/hip_runtime.h>
#include <cstddef>

typedef _Float16 f16x8 __attribute__((ext_vector_type(8)));
typedef _Float16 f16x2 __attribute__((ext_vector_type(2)));
typedef float    f32x4 __attribute__((ext_vector_type(4)));

#define Bc 4096
#define Tc 256
#define NSTEP 257
#define RB 16               // rows per block
#define HSTR 264            // fp16 h-tile row stride (528B: b128 reads conflict-free)
#define GSTR 12             // gateC dwords per unit (bank-spread for b128 pairs)
#define HEAD_OFF 393216     // byte offset of head frags in ws

__device__ inline float sigm(float x)  { return __builtin_amdgcn_rcpf(1.f + __expf(-x)); }
__device__ inline float tanh_(float x) { return 1.f - 2.f * __builtin_amdgcn_rcpf(1.f + __expf(2.f * x)); }

// ---------------------------------------------------------------------------
// Build fragment-linear fp16 copies of w_hh and w_head in ws.
// GRU frag f = (trio*3+nc)*8 + kt, 1024 B each, trio = 2*w + p.
// EVEN/ODD PAIRING: tile (w,p) column c holds unit  32w + 2c + p
//   -> thread (w, l15) owns ADJACENT units u0=32w+2*l15 (p=0), u0+1 (p=1),
//      enabling packed b32 h-writes in the gate phase.
//   element (lane l, j) = W[kt*32 + (l>>4)*8 + j][nc*256 + 32*(trio>>1) + 2*(l&15) + (trio&1)]
// head frags at HEAD_OFF, kt = 0..7: col = l&15 (<2 real, else 0) (unpermuted)
// ---------------------------------------------------------------------------
__global__ __launch_bounds__(256) void build_frags(
    const float* __restrict__ w_hh, const float* __restrict__ w_head,
    _Float16* __restrict__ ws)
{
    int flat = blockIdx.x * 256 + threadIdx.x;
    if (blockIdx.x < 96) {
        int f    = flat >> 6;          // 0..383
        int lane = flat & 63;
        int kt   = f & 7;
        int nc   = (f >> 3) % 3;
        int trio = f / 24;
        int c     = nc * 256 + (trio >> 1) * 32 + 2 * (lane & 15) + (trio & 1);
        int kbase = kt * 32 + (lane >> 4) * 8;
        _Float16* dst = ws + (size_t)f * 512 + (size_t)lane * 8;
        #pragma unroll
        for (int j = 0; j < 8; ++j)
            dst[j] = (_Float16)w_hh[(size_t)(kbase + j) * 768 + c];
    } else {
        int idx = flat - 96 * 256;     // 0..511
        int kt   = idx >> 6;
        int lane = idx & 63;
        int col   = lane & 15;
        int kbase = kt * 32 + (lane >> 4) * 8;
        _Float16* dst = ws + HEAD_OFF / 2 + (size_t)kt * 512 + (size_t)lane * 8;
        #pragma unroll
        for (int j = 0; j < 8; ++j)
            dst[j] = (col < 2) ? (_Float16)w_head[(size_t)(kbase + j) * 2 + col]
                               : (_Float16)0.f;
    }
}

// ---------------------------------------------------------------------------
// GRU scan: 256 blocks x 512 threads (8 waves), 16 rows per block.
// R4-proven structure: TWO barriers/step, single h16 buffer, hold (f32
// recurrence state) in registers, 48 B-frags register/AGPR-resident.
// New: even/odd unit pairing -> 4 packed ds_write_b32 h-updates (was 8 b16,
// 4-way conflicted); gateC stride 12 (2-way banks); xs as 1 ds_read_b128.
// Head fused on wave 0; output staged in parity outbuf, flushed as 64B lines.
// ---------------------------------------------------------------------------
__global__ __attribute__((amdgpu_waves_per_eu(2, 2))) __launch_bounds__(512)
void gru_mfma(
    const float* __restrict__ cond, const float* __restrict__ ivf,
    const float* __restrict__ times,
    const float* __restrict__ w1, const float* __restrict__ b1,
    const float* __restrict__ w2, const float* __restrict__ b2,
    const float* __restrict__ w3, const float* __restrict__ b3,
    const float* __restrict__ wh0, const float* __restrict__ bh0,
    const float* __restrict__ w_ih, const float* __restrict__ b_ih,
    const float* __restrict__ b_hh, const float* __restrict__ b_head,
    const _Float16* __restrict__ wfrag,
    float* __restrict__ out)
{
    __shared__ __align__(16) _Float16 h16[RB * HSTR];     // 8448 B
    __shared__ __align__(16) float xs4[4 * NSTEP * 4];    // 16448 B [q][i][4]
    __shared__ __align__(16) _Float16 headB[4096];        // 8192 B
    __shared__ __align__(16) float gateC[256 * GSTR];     // 12288 B
    __shared__ float  outbuf[2][2][RB][16];               // 4096 B [parity][plane][row][slot]
    __shared__ float  bh2[2];
    __shared__ float  mlp1[RB * 128];                     // 8192 B
    __shared__ float  mlp2[RB * 128];                     // 8192 B
    __shared__ float  embS[RB * 64];                      // 4096 B
    __shared__ float  h0f[RB * 256];                      // 16384 B

    const int tid  = threadIdx.x;
    const int w    = tid >> 6;
    const int lane = tid & 63;
    const int l15  = lane & 15;
    const int q    = lane >> 4;
    const int row0 = blockIdx.x * RB;

    // ---- preamble: MLP + h0 for the block's 16 rows ----
    for (int o = tid; o < RB * 128; o += 512) {
        int r = o >> 7, c = o & 127;
        float a = b1[c];
        #pragma unroll 4
        for (int k = 0; k < 64; ++k)
            a = fmaf(ivf[(size_t)(row0 + r) * 64 + k], w1[k * 128 + c], a);
        mlp1[o] = fmaxf(a, 0.f);
    }
    __syncthreads();
    for (int o = tid; o < RB * 128; o += 512) {
        int r = o >> 7, c = o & 127;
        float a = b2[c];
        #pragma unroll 4
        for (int k = 0; k < 128; ++k)
            a = fmaf(mlp1[r * 128 + k], w2[k * 128 + c], a);
        mlp2[o] = fmaxf(a, 0.f);
    }
    __syncthreads();
    for (int o = tid; o < RB * 64; o += 512) {
        int r = o >> 6, c = o & 63;
        float a = b3[c];
        #pragma unroll 4
        for (int k = 0; k < 128; ++k)
            a = fmaf(mlp2[r * 128 + k], w3[k * 64 + c], a);
        embS[o] = a;
    }
    __syncthreads();
    for (int o = tid; o < RB * 256; o += 512) {
        int r = o >> 8, c = o & 255;
        float a = bh0[c];
        #pragma unroll 4
        for (int k = 0; k < 128; ++k)
            a = fmaf(cond[(size_t)(row0 + r) * 128 + k], wh0[k * 256 + c], a);
        #pragma unroll 4
        for (int k = 0; k < 64; ++k)
            a = fmaf(embS[r * 64 + k], wh0[(128 + k) * 256 + c], a);
        float h = tanh_(a);
        h0f[o] = h;
        h16[r * HSTR + c] = (_Float16)h;
    }

    // xs4 table, head-B staging, gate-constant table
    for (int o = tid; o < 4 * NSTEP; o += 512) {
        int qg = o / NSTEP, ii = o - qg * NSTEP;
        #pragma unroll
        for (int jj = 0; jj < 4; ++jj) {
            int r = qg * 4 + jj;
            float x = 0.f;
            if (ii >= 1) {
                float a = times[(size_t)(row0 + r) * Tc + (ii - 1)];
                float b = (ii >= 2) ? times[(size_t)(row0 + r) * Tc + (ii - 2)] : 0.f;
                x = a - b;
            }
            xs4[o * 4 + jj] = x;
        }
    }
    {
        const float4* src = (const float4*)(wfrag + HEAD_OFF / 2);
        ((float4*)headB)[tid] = src[tid];
    }
    for (int uu = tid; uu < 256; uu += 512) {
        gateC[uu * GSTR + 0] = w_ih[uu];
        gateC[uu * GSTR + 1] = w_ih[256 + uu];
        gateC[uu * GSTR + 2] = w_ih[512 + uu];
        gateC[uu * GSTR + 3] = b_ih[uu] + b_hh[uu];
        gateC[uu * GSTR + 4] = b_ih[256 + uu] + b_hh[256 + uu];
        gateC[uu * GSTR + 5] = b_ih[512 + uu];
        gateC[uu * GSTR + 6] = b_hh[512 + uu];
        gateC[uu * GSTR + 7] = 0.f;
    }
    if (tid < 2) bh2[tid] = b_head[tid];

    // ---- register-resident weight fragments: 48 x f16x8 ----
    const int u0 = w * 32 + 2 * l15;       // even unit (p=0 tile col l15)
    const int u1 = u0 + 1;                 // odd unit  (p=1 tile col l15)

    f16x8 Bf[2][3][8];
    #pragma unroll
    for (int p = 0; p < 2; ++p)
        #pragma unroll
        for (int nc = 0; nc < 3; ++nc)
            #pragma unroll
            for (int kt = 0; kt < 8; ++kt)
                Bf[p][nc][kt] = *(const f16x8*)(wfrag
                    + (size_t)(((2 * w + p) * 3 + nc) * 8 + kt) * 512
                    + (size_t)lane * 8);

    __syncthreads();

    float hold[2][4];
    #pragma unroll
    for (int p = 0; p < 2; ++p)
        #pragma unroll
        for (int j = 0; j < 4; ++j)
            hold[p][j] = h0f[(q * 4 + j) * 256 + u0 + p];

    // ---- 257 GRU steps + 1 head-only epilogue; 2 barriers/step ----
    for (int i = 0; i <= NSTEP; ++i) {
        const bool doGh = (i < NSTEP);
        const bool doHd = (i >= 1) && (w == 0);

        // flush a completed 16-output chunk (chunk 16k complete after step
        // 16k+16 phase A; flushed at step 16k+17, >=2 barriers later)
        if (i >= 17 && ((i - 17) & 15) == 0) {
            const int obase = i - 17;
            const int par   = (obase >> 4) & 1;
            const int e     = tid & 15;
            const int row   = (tid >> 4) & 15;
            const int plane = tid >> 8;
            out[(size_t)plane * ((size_t)Bc * NSTEP)
                + (size_t)(row0 + row) * NSTEP + obase + e]
                = outbuf[par][plane][row][e] + bh2[plane];
        }

        f32x4 aR[2], aZ[2], aN[2];
        #pragma unroll
        for (int p = 0; p < 2; ++p) {
            aR[p] = (f32x4){0.f, 0.f, 0.f, 0.f};
            aZ[p] = (f32x4){0.f, 0.f, 0.f, 0.f};
            aN[p] = (f32x4){0.f, 0.f, 0.f, 0.f};
        }
        f32x4 aH = (f32x4){0.f, 0.f, 0.f, 0.f};

        // phase A: MFMA
        const _Float16* abase = h16 + l15 * HSTR + q * 8;
        #pragma unroll
        for (int kt = 0; kt < 8; ++kt) {
            if (doGh || doHd) {
                f16x8 Af = *(const f16x8*)(abase + kt * 32);
                if (doGh) {
                    #pragma unroll
                    for (int p = 0; p < 2; ++p) {
                        aR[p] = __builtin_amdgcn_mfma_f32_16x16x32_f16(Af, Bf[p][0][kt], aR[p], 0, 0, 0);
                        aZ[p] = __builtin_amdgcn_mfma_f32_16x16x32_f16(Af, Bf[p][1][kt], aZ[p], 0, 0, 0);
                        aN[p] = __builtin_amdgcn_mfma_f32_16x16x32_f16(Af, Bf[p][2][kt], aN[p], 0, 0, 0);
                    }
                }
                if (doHd) {
                    f16x8 Bh = *(const f16x8*)(headB + kt * 512 + lane * 8);
                    aH = __builtin_amdgcn_mfma_f32_16x16x32_f16(Af, Bh, aH, 0, 0, 0);
                }
            }
        }

        // stage head results (w0, 2 lanes per q-group), parity buffer
        if (doHd && l15 < 2) {
            const int o = i - 1;
            #pragma unroll
            for (int j = 0; j < 4; ++j)
                outbuf[(o >> 4) & 1][l15][q * 4 + j][o & 15] = aH[j];
        }

        __syncthreads();   // all phase-A reads of h_i complete

        // phase B: gates -> h_{i+1}; packed b32 writes (adjacent unit pair)
        if (doGh) {
            const f32x4 xv  = *(const f32x4*)(xs4 + (q * NSTEP + i) * 4);
            const f32x4 g0a = *(const f32x4*)(gateC + u0 * GSTR);
            const f32x4 g1a = *(const f32x4*)(gateC + u0 * GSTR + 4);
            const f32x4 g0b = *(const f32x4*)(gateC + u1 * GSTR);
            const f32x4 g1b = *(const f32x4*)(gateC + u1 * GSTR + 4);
            #pragma unroll
            for (int j = 0; j < 4; ++j) {
                const int m = q * 4 + j;
                const float x = xv[j];

                const float rr0 = sigm(fmaf(x, g0a[0], g0a[3]) + aR[0][j]);
                const float zz0 = sigm(fmaf(x, g0a[1], g1a[0]) + aZ[0][j]);
                const float nn0 = tanh_(fmaf(x, g0a[2], g1a[1]) + rr0 * (aN[0][j] + g1a[2]));
                const float h0_ = nn0 + zz0 * (hold[0][j] - nn0);
                hold[0][j] = h0_;

                const float rr1 = sigm(fmaf(x, g0b[0], g0b[3]) + aR[1][j]);
                const float zz1 = sigm(fmaf(x, g0b[1], g1b[0]) + aZ[1][j]);
                const float nn1 = tanh_(fmaf(x, g0b[2], g1b[1]) + rr1 * (aN[1][j] + g1b[2]));
                const float h1_ = nn1 + zz1 * (hold[1][j] - nn1);
                hold[1][j] = h1_;

                *(f16x2*)(h16 + m * HSTR + u0) = (f16x2){(_Float16)h0_, (_Float16)h1_};
            }
        }
        __syncthreads();   // h_{i+1} visible for next step's phase A
    }

    // final flush: output index 256 (parity 0), staged at step 257
    {
        const int e     = tid & 15;
        const int row   = (tid >> 4) & 15;
        const int plane = tid >> 8;
        if (e < 1) {
            out[(size_t)plane * ((size_t)Bc * NSTEP)
                + (size_t)(row0 + row) * NSTEP + 256 + e]
                = outbuf[0][plane][row][e] + bh2[plane];
        }
    }
}

// ---------------------------------------------------------------------------
extern "C" void kernel_launch(void* const* d_in, const int* in_sizes, int n_in,
                              void* d_out, int out_size, void* d_ws, size_t ws_size,
                              hipStream_t stream) {
    const float* cond   = (const float*)d_in[0];
    const float* ivf    = (const float*)d_in[1];
    const float* times  = (const float*)d_in[2];
    // d_in[3] = seq_lens (unused by reference)
    const float* w1     = (const float*)d_in[4];
    const float* b1     = (const float*)d_in[5];
    const float* w2     = (const float*)d_in[6];
    const float* b2     = (const float*)d_in[7];
    const float* w3     = (const float*)d_in[8];
    const float* b3     = (const float*)d_in[9];
    const float* wh0    = (const float*)d_in[10];
    const float* bh0    = (const float*)d_in[11];
    const float* w_ih   = (const float*)d_in[12];
    const float* b_ih   = (const float*)d_in[13];
    const float* w_hh   = (const float*)d_in[14];
    const float* b_hh   = (const float*)d_in[15];
    const float* w_head = (const float*)d_in[16];
    const float* b_head = (const float*)d_in[17];

    float*    outp = (float*)d_out;
    _Float16* ws   = (_Float16*)d_ws;

    build_frags<<<98, 256, 0, stream>>>(w_hh, w_head, ws);
    gru_mfma<<<Bc / RB, 512, 0, stream>>>(cond, ivf, times,
                                          w1, b1, w2, b2, w3, b3, wh0, bh0,
                                          w_ih, b_ih, b_hh, b_head,
                                          (const _Float16*)ws, outp);
}

// Round 9
// 696.703 us; speedup vs baseline: 1.2198x; 1.0121x over previous
//
#include <hip/hip_runtime.h>
#include <cstddef>

typedef _Float16 f16x8 __attribute__((ext_vector_type(8)));
typedef _Float16 f16x2 __attribute__((ext_vector_type(2)));
typedef float    f32x4 __attribute__((ext_vector_type(4)));

#define Bc 4096
#define Tc 256
#define NSTEP 257
#define RB 16               // rows per block
#define HSTR 264            // fp16 h-tile row stride (528B)
#define FSTR 260            // f32 hF row stride (2-way banks = free)
#define GSTR 12             // gateC dwords per unit
#define HEAD_OFF 393216     // byte offset of head frags in ws

__device__ inline float sigm(float x)  { return __builtin_amdgcn_rcpf(1.f + __expf(-x)); }
__device__ inline float tanh_(float x) { return 1.f - 2.f * __builtin_amdgcn_rcpf(1.f + __expf(2.f * x)); }

// ---------------------------------------------------------------------------
// Build fragment-linear fp16 copies of w_hh and w_head in ws.
// GRU frag f = (trio*3+nc)*8 + kt, 1024 B each, trio = 2*w + p.
// EVEN/ODD PAIRING: tile (w,p) column c holds unit 32w + 2c + p
//   element (lane l, j) = W[kt*32 + (l>>4)*8 + j][nc*256 + 32*(trio>>1) + 2*(l&15) + (trio&1)]
// head frags at HEAD_OFF, kt = 0..7: col = l&15 (<2 real, else 0)
// ---------------------------------------------------------------------------
__global__ __launch_bounds__(256) void build_frags(
    const float* __restrict__ w_hh, const float* __restrict__ w_head,
    _Float16* __restrict__ ws)
{
    int flat = blockIdx.x * 256 + threadIdx.x;
    if (blockIdx.x < 96) {
        int f    = flat >> 6;          // 0..383
        int lane = flat & 63;
        int kt   = f & 7;
        int nc   = (f >> 3) % 3;
        int trio = f / 24;
        int c     = nc * 256 + (trio >> 1) * 32 + 2 * (lane & 15) + (trio & 1);
        int kbase = kt * 32 + (lane >> 4) * 8;
        _Float16* dst = ws + (size_t)f * 512 + (size_t)lane * 8;
        #pragma unroll
        for (int j = 0; j < 8; ++j)
            dst[j] = (_Float16)w_hh[(size_t)(kbase + j) * 768 + c];
    } else {
        int idx = flat - 96 * 256;     // 0..511
        int kt   = idx >> 6;
        int lane = idx & 63;
        int col   = lane & 15;
        int kbase = kt * 32 + (lane >> 4) * 8;
        _Float16* dst = ws + HEAD_OFF / 2 + (size_t)kt * 512 + (size_t)lane * 8;
        #pragma unroll
        for (int j = 0; j < 8; ++j)
            dst[j] = (col < 2) ? (_Float16)w_head[(size_t)(kbase + j) * 2 + col]
                               : (_Float16)0.f;
    }
}

// ---------------------------------------------------------------------------
// GRU scan: 256 blocks x 512 threads (8 waves), 16 rows per block.
// REGISTER DIET (unified 256/wave cap at 2 waves/EU): Bf 192 + acc 28 kept;
// hold -> LDS hF; gate consts transient per-p; xs scalar reads. ~245 total.
// BARRIER PLACEMENT: fat phase [flush | MFMA | gates] runs barrier-free ->
// waves drift, MFMA overlaps gate-VALU across waves; the two barriers
// bracket only the 4x ds_write_b32 h16-update.
// ---------------------------------------------------------------------------
__global__ __attribute__((amdgpu_waves_per_eu(2, 2))) __launch_bounds__(512)
void gru_mfma(
    const float* __restrict__ cond, const float* __restrict__ ivf,
    const float* __restrict__ times,
    const float* __restrict__ w1, const float* __restrict__ b1,
    const float* __restrict__ w2, const float* __restrict__ b2,
    const float* __restrict__ w3, const float* __restrict__ b3,
    const float* __restrict__ wh0, const float* __restrict__ bh0,
    const float* __restrict__ w_ih, const float* __restrict__ b_ih,
    const float* __restrict__ b_hh, const float* __restrict__ b_head,
    const _Float16* __restrict__ wfrag,
    float* __restrict__ out)
{
    __shared__ __align__(16) _Float16 h16[RB * HSTR];     // 8448 B
    __shared__ __align__(8)  float hF[RB * FSTR];         // 16640 B f32 h-state
    __shared__ __align__(16) float xs4[4 * NSTEP * 4];    // 16448 B [q][i][4]
    __shared__ __align__(16) _Float16 headB[4096];        // 8192 B
    __shared__ __align__(16) float gateC[256 * GSTR];     // 12288 B
    __shared__ float  outbuf[2][2][RB][16];               // 4096 B
    __shared__ float  bh2[2];
    __shared__ float  mlp1[RB * 128];                     // 8192 B
    __shared__ float  mlp2[RB * 128];                     // 8192 B
    __shared__ float  embS[RB * 64];                      // 4096 B
    __shared__ float  h0f[RB * 256];                      // 16384 B

    const int tid  = threadIdx.x;
    const int w    = tid >> 6;
    const int lane = tid & 63;
    const int l15  = lane & 15;
    const int q    = lane >> 4;
    const int row0 = blockIdx.x * RB;

    // ---- preamble: MLP + h0 for the block's 16 rows ----
    for (int o = tid; o < RB * 128; o += 512) {
        int r = o >> 7, c = o & 127;
        float a = b1[c];
        #pragma unroll 4
        for (int k = 0; k < 64; ++k)
            a = fmaf(ivf[(size_t)(row0 + r) * 64 + k], w1[k * 128 + c], a);
        mlp1[o] = fmaxf(a, 0.f);
    }
    __syncthreads();
    for (int o = tid; o < RB * 128; o += 512) {
        int r = o >> 7, c = o & 127;
        float a = b2[c];
        #pragma unroll 4
        for (int k = 0; k < 128; ++k)
            a = fmaf(mlp1[r * 128 + k], w2[k * 128 + c], a);
        mlp2[o] = fmaxf(a, 0.f);
    }
    __syncthreads();
    for (int o = tid; o < RB * 64; o += 512) {
        int r = o >> 6, c = o & 63;
        float a = b3[c];
        #pragma unroll 4
        for (int k = 0; k < 128; ++k)
            a = fmaf(mlp2[r * 128 + k], w3[k * 64 + c], a);
        embS[o] = a;
    }
    __syncthreads();
    for (int o = tid; o < RB * 256; o += 512) {
        int r = o >> 8, c = o & 255;
        float a = bh0[c];
        #pragma unroll 4
        for (int k = 0; k < 128; ++k)
            a = fmaf(cond[(size_t)(row0 + r) * 128 + k], wh0[k * 256 + c], a);
        #pragma unroll 4
        for (int k = 0; k < 64; ++k)
            a = fmaf(embS[r * 64 + k], wh0[(128 + k) * 256 + c], a);
        float h = tanh_(a);
        h0f[o] = h;
        h16[r * HSTR + c] = (_Float16)h;
    }

    // xs4 table, head-B staging, gate-constant table
    for (int o = tid; o < 4 * NSTEP; o += 512) {
        int qg = o / NSTEP, ii = o - qg * NSTEP;
        #pragma unroll
        for (int jj = 0; jj < 4; ++jj) {
            int r = qg * 4 + jj;
            float x = 0.f;
            if (ii >= 1) {
                float a = times[(size_t)(row0 + r) * Tc + (ii - 1)];
                float b = (ii >= 2) ? times[(size_t)(row0 + r) * Tc + (ii - 2)] : 0.f;
                x = a - b;
            }
            xs4[o * 4 + jj] = x;
        }
    }
    {
        const float4* src = (const float4*)(wfrag + HEAD_OFF / 2);
        ((float4*)headB)[tid] = src[tid];
    }
    for (int uu = tid; uu < 256; uu += 512) {
        gateC[uu * GSTR + 0] = w_ih[uu];
        gateC[uu * GSTR + 1] = w_ih[256 + uu];
        gateC[uu * GSTR + 2] = w_ih[512 + uu];
        gateC[uu * GSTR + 3] = b_ih[uu] + b_hh[uu];
        gateC[uu * GSTR + 4] = b_ih[256 + uu] + b_hh[256 + uu];
        gateC[uu * GSTR + 5] = b_ih[512 + uu];
        gateC[uu * GSTR + 6] = b_hh[512 + uu];
        gateC[uu * GSTR + 7] = 0.f;
    }
    if (tid < 2) bh2[tid] = b_head[tid];

    // ---- register-resident weight fragments + hF init ----
    const int u0 = w * 32 + 2 * l15;       // even unit
    const int u1 = u0 + 1;                 // odd unit

    f16x8 Bf[2][3][8];
    #pragma unroll
    for (int p = 0; p < 2; ++p)
        #pragma unroll
        for (int nc = 0; nc < 3; ++nc)
            #pragma unroll
            for (int kt = 0; kt < 8; ++kt)
                Bf[p][nc][kt] = *(const f16x8*)(wfrag
                    + (size_t)(((2 * w + p) * 3 + nc) * 8 + kt) * 512
                    + (size_t)lane * 8);

    #pragma unroll
    for (int j = 0; j < 4; ++j) {
        const int m = q * 4 + j;
        *(float2*)(hF + m * FSTR + u0) =
            (float2){h0f[m * 256 + u0], h0f[m * 256 + u1]};
    }

    __syncthreads();

    // ---- 257 GRU steps + 1 head-only epilogue ----
    for (int i = 0; i <= NSTEP; ++i) {
        const bool doGh = (i < NSTEP);
        const bool doHd = (i >= 1) && (w == 0);

        // 1. flush a completed 16-output chunk (written >=1 barrier-pair ago)
        if (i >= 17 && ((i - 17) & 15) == 0) {
            const int obase = i - 17;
            const int par   = (obase >> 4) & 1;
            const int e     = tid & 15;
            const int row   = (tid >> 4) & 15;
            const int plane = tid >> 8;
            out[(size_t)plane * ((size_t)Bc * NSTEP)
                + (size_t)(row0 + row) * NSTEP + obase + e]
                = outbuf[par][plane][row][e] + bh2[plane];
        }

        f32x4 aR[2], aZ[2], aN[2];
        #pragma unroll
        for (int p = 0; p < 2; ++p) {
            aR[p] = (f32x4){0.f, 0.f, 0.f, 0.f};
            aZ[p] = (f32x4){0.f, 0.f, 0.f, 0.f};
            aN[p] = (f32x4){0.f, 0.f, 0.f, 0.f};
        }
        f32x4 aH = (f32x4){0.f, 0.f, 0.f, 0.f};

        // 2. MFMA (reads h16 of step i)
        const _Float16* abase = h16 + l15 * HSTR + q * 8;
        #pragma unroll
        for (int kt = 0; kt < 8; ++kt) {
            if (doGh || doHd) {
                f16x8 Af = *(const f16x8*)(abase + kt * 32);
                if (doGh) {
                    #pragma unroll
                    for (int p = 0; p < 2; ++p) {
                        aR[p] = __builtin_amdgcn_mfma_f32_16x16x32_f16(Af, Bf[p][0][kt], aR[p], 0, 0, 0);
                        aZ[p] = __builtin_amdgcn_mfma_f32_16x16x32_f16(Af, Bf[p][1][kt], aZ[p], 0, 0, 0);
                        aN[p] = __builtin_amdgcn_mfma_f32_16x16x32_f16(Af, Bf[p][2][kt], aN[p], 0, 0, 0);
                    }
                }
                if (doHd) {
                    f16x8 Bh = *(const f16x8*)(headB + kt * 512 + lane * 8);
                    aH = __builtin_amdgcn_mfma_f32_16x16x32_f16(Af, Bh, aH, 0, 0, 0);
                }
            }
        }

        // 3. stage head results (w0-private outbuf; flushed >=1 barrier later)
        if (doHd && l15 < 2) {
            const int o = i - 1;
            #pragma unroll
            for (int j = 0; j < 4; ++j)
                outbuf[(o >> 4) & 1][l15][q * 4 + j][o & 15] = aH[j];
        }

        // 4. gates (no h16 access): f32 state in hF (thread-private), h_new
        //    packed into 4 VGPRs for the post-barrier write
        f16x2 hnew0, hnew1, hnew2, hnew3;
        if (doGh) {
            float t0[4], t1[4];
            #pragma unroll
            for (int p = 0; p < 2; ++p) {
                const int u = p ? u1 : u0;
                const f32x4 g0 = *(const f32x4*)(gateC + u * GSTR);      // wiR,wiZ,wiN,bR
                const f32x4 g1 = *(const f32x4*)(gateC + u * GSTR + 4);  // bZ,biN,bhN,pad
                float* tp = p ? t1 : t0;
                #pragma unroll
                for (int j = 0; j < 4; ++j) {
                    const int m = q * 4 + j;
                    const float x  = xs4[(q * NSTEP + i) * 4 + j];
                    const float ho = hF[m * FSTR + u];
                    const float rr = sigm(fmaf(x, g0[0], g0[3]) + aR[p][j]);
                    const float zz = sigm(fmaf(x, g0[1], g1[0]) + aZ[p][j]);
                    const float nn = tanh_(fmaf(x, g0[2], g1[1]) + rr * (aN[p][j] + g1[2]));
                    const float hn = nn + zz * (ho - nn);
                    hF[m * FSTR + u] = hn;
                    tp[j] = hn;
                }
            }
            hnew0 = (f16x2){(_Float16)t0[0], (_Float16)t1[0]};
            hnew1 = (f16x2){(_Float16)t0[1], (_Float16)t1[1]};
            hnew2 = (f16x2){(_Float16)t0[2], (_Float16)t1[2]};
            hnew3 = (f16x2){(_Float16)t0[3], (_Float16)t1[3]};
        }

        __syncthreads();   // all fat-phase reads of h16 (step i) complete

        // 5. write phase: 4 packed b32 stores, bracketed by the barriers
        if (doGh) {
            _Float16* hb = h16 + (q * 4) * HSTR + u0;
            *(f16x2*)(hb)            = hnew0;
            *(f16x2*)(hb + HSTR)     = hnew1;
            *(f16x2*)(hb + 2 * HSTR) = hnew2;
            *(f16x2*)(hb + 3 * HSTR) = hnew3;
        }
        __syncthreads();   // h_{i+1} visible for next step's MFMA
    }

    // final flush: output index 256 (parity 0), staged at step 257
    {
        const int e     = tid & 15;
        const int row   = (tid >> 4) & 15;
        const int plane = tid >> 8;
        if (e < 1) {
            out[(size_t)plane * ((size_t)Bc * NSTEP)
                + (size_t)(row0 + row) * NSTEP + 256 + e]
                = outbuf[0][plane][row][e] + bh2[plane];
        }
    }
}

// ---------------------------------------------------------------------------
extern "C" void kernel_launch(void* const* d_in, const int* in_sizes, int n_in,
                              void* d_out, int out_size, void* d_ws, size_t ws_size,
                              hipStream_t stream) {
    const float* cond   = (const float*)d_in[0];
    const float* ivf    = (const float*)d_in[1];
    const float* times  = (const float*)d_in[2];
    // d_in[3] = seq_lens (unused by reference)
    const float* w1     = (const float*)d_in[4];
    const float* b1     = (const float*)d_in[5];
    const float* w2     = (const float*)d_in[6];
    const float* b2     = (const float*)d_in[7];
    const float* w3     = (const float*)d_in[8];
    const float* b3     = (const float*)d_in[9];
    const float* wh0    = (const float*)d_in[10];
    const float* bh0    = (const float*)d_in[11];
    const float* w_ih   = (const float*)d_in[12];
    const float* b_ih   = (const float*)d_in[13];
    const float* w_hh   = (const float*)d_in[14];
    const float* b_hh   = (const float*)d_in[15];
    const float* w_head = (const float*)d_in[16];
    const float* b_head = (const float*)d_in[17];

    float*    outp = (float*)d_out;
    _Float16* ws   = (_Float16*)d_ws;

    build_frags<<<98, 256, 0, stream>>>(w_hh, w_head, ws);
    gru_mfma<<<Bc / RB, 512, 0, stream>>>(cond, ivf, times,
                                          w1, b1, w2, b2, w3, b3, wh0, bh0,
                                          w_ih, b_ih, b_hh, b_head,
                                          (const _Float16*)ws, outp);
}